// Round 24
// baseline (107.798 us; speedup 1.0000x reference)
//
#include <hip/hip_runtime.h>

#define B_    1024
#define AB_   6
#define BIN_  16
#define BOUT_ 32

typedef float f4 __attribute__((ext_vector_type(4)));
typedef _Float16 hlf4 __attribute__((ext_vector_type(4)));

#define SOFTBAR()                                                  \
    do {                                                           \
        asm volatile("s_waitcnt lgkmcnt(0)" ::: "memory");         \
        __builtin_amdgcn_s_barrier();                              \
        __builtin_amdgcn_sched_barrier(0);                         \
    } while (0)

// out[slice, o, l, k] = sum_i X[slice, i, l] * W[ab, i, o, k]
//
// R24 = R23 + G-deep slice staging per barrier pair + longer-lived blocks.
// R22/R23 readout: l8 body alone = 6.5 TB/s at only 3 blocks/CU (occupancy
// and 2-phase structure are NOT binding); the fused kernel's 4.6 TB/s
// average is dragged by the small degrees' bytes-per-barrier (l2: 3.2 KB
// per barrier pair) and by per-block prologue churn (4704 short blocks).
// Fix: stage G slices per phase (one barrier pair flushes G dense regions)
// and raise SPB. Geometry: l8 half/G1/SPB16 (18.5 KB), l6 full/G1/SPB16
// (21.6 KB), l4 G2/SPB16 (20.7 KB), l2 G4/SPB32 (12.8 KB). Blocks 1824.
template<int NSH, int OH, int G, int SPB>
__device__ __forceinline__ void mfma_lds_body(const float* __restrict__ X,
                                              const float* __restrict__ W,
                                              float* __restrict__ OUT,
                                              float* os, int b) {
    constexpr int OPB  = BOUT_ / OH;           // o's per block
    constexpr int SZ   = BIN_ * NSH;
    constexpr int NOUT = BOUT_ * NSH * NSH;
    constexpr int USZ  = OPB * NSH * NSH;      // floats per staged slice
    constexpr int NTU  = (OPB * NSH) / 16;     // N-tiles per slice
    constexpr int MT   = (NSH + 15) / 16;      // M-tiles (tail rows masked)
    constexpr int NTQ  = (NTU + 3) / 4;        // N-tiles per wave
    constexpr int NG   = SPB / G;              // phase groups per block
    static_assert(SPB % G == 0, "group geometry");

    const int tid  = threadIdx.x;
    const int lane = tid & 63;
    const int w    = tid >> 6;                 // wave 0..3
    const int lm   = lane & 15;                // A-row / B-col / D-col
    const int lk   = (lane >> 4) * 4;          // A/B k-chunk; D row-chunk

    const int h  = (OH == 2) ? (b & 1) : 0;    // o-half
    const int gi = (OH == 2) ? (b >> 1) : b;
    const int ab = gi % AB_;
    const int gb = gi / AB_;
    const int t0 = gb * SPB;

    const float* Wab = W + (size_t)ab * (BIN_ * BOUT_ * NSH);

    // ---- hoist this wave's B-frags once per block (this block's o-range) ----
    hlf4 bfrag[NTQ];
#pragma unroll
    for (int t = 0; t < NTQ; ++t) {
        const int ni = w * NTQ + t;
        if (ni < NTU) {
            const int n = h * (OPB * NSH) + ni * 16 + lm;
#pragma unroll
            for (int j = 0; j < 4; ++j)
                bfrag[t][j] = (_Float16)Wab[(lk + j) * (BOUT_ * NSH) + n];
        }
    }

    auto load_group = [&](int ng, hlf4 (*dst)[MT]) {   // A[row=l][k] = X[k][l]
#pragma unroll
        for (int g = 0; g < G; ++g) {
            const float* Xs = X + (size_t)(ab + AB_ * (t0 + ng * G + g)) * SZ;
#pragma unroll
            for (int mi = 0; mi < MT; ++mi) {
                const int l  = mi * 16 + lm;
                const int lc = (l > NSH - 1) ? (NSH - 1) : l;  // clamp, masked later
#pragma unroll
                for (int j = 0; j < 4; ++j)
                    dst[g][mi][j] = (_Float16)Xs[(lk + j) * NSH + lc];
            }
        }
    };

    hlf4 acur[G][MT], anext[G][MT];
    load_group(0, acur);                        // prologue

    for (int ng = 0; ng < NG; ++ng) {
        // ---- compute G slices into G LDS regions ----
#pragma unroll
        for (int g = 0; g < G; ++g) {
            float* buf = os + g * USZ;
#pragma unroll
            for (int t = 0; t < NTQ; ++t) {
                const int ni = w * NTQ + t;
                if (ni < NTU) {
                    const int nl = ni * 16 + lm;
                    const int ol = nl / NSH;     // constexpr divisor -> magic mul
                    const int kq = nl - ol * NSH;
                    float* base = buf + ol * (NSH * NSH) + kq;
#pragma unroll
                    for (int mi = 0; mi < MT; ++mi) {
                        f4 d = __builtin_amdgcn_mfma_f32_16x16x16f16(
                            acur[g][mi], bfrag[t], (f4){0.f, 0.f, 0.f, 0.f}, 0, 0, 0);
#pragma unroll
                        for (int j = 0; j < 4; ++j) {
                            const int l = mi * 16 + lk + j;   // D row
                            if (l < NSH) base[l * NSH] = d[j];
                        }
                    }
                }
            }
        }
        SOFTBAR();   // ds_writes visible; global stores stay in flight

        // ---- prefetch next group's A-frags (hides under flush) ----
        if (ng + 1 < NG) load_group(ng + 1, anext);

        // ---- dense contiguous f4 flush of G regions ----
#pragma unroll
        for (int g = 0; g < G; ++g) {
            f4* dst = (f4*)(OUT + (size_t)(ab + AB_ * (t0 + ng * G + g)) * NOUT
                            + (size_t)h * USZ);
            const f4* src = (const f4*)(os + g * USZ);
            for (int c = tid; c < USZ / 4; c += 256) dst[c] = src[c];
        }
        SOFTBAR();   // flush ds_reads done -> buffers reusable

#pragma unroll
        for (int g = 0; g < G; ++g)
#pragma unroll
            for (int mi = 0; mi < MT; ++mi) acur[g][mi] = anext[g][mi];
    }
}

// l=0: direct coalesced stores, 64 n per block.
__device__ __forceinline__ void l0_body(const float* __restrict__ X,
                                        const float* __restrict__ W,
                                        const float* __restrict__ bias,
                                        float* __restrict__ OUT, int b) {
    const int o  = threadIdx.x & 31;
    const int ns = threadIdx.x >> 5;   // 0..7
    const int n0 = (b / AB_) * 64;
    const int ab = b % AB_;
    float wv[BIN_];
#pragma unroll
    for (int i = 0; i < BIN_; ++i) wv[i] = W[(ab * BIN_ + i) * BOUT_ + o];
    const float bv = bias[ab * BOUT_ + o];
#pragma unroll
    for (int s = 0; s < 8; ++s) {
        const int n = n0 + ns + s * 8;
        const float* Xp = X + ((size_t)n * AB_ + ab) * BIN_;
        float acc = bv;
#pragma unroll
        for (int i = 0; i < BIN_; ++i) acc = fmaf(Xp[i], wv[i], acc);
        OUT[((size_t)n * AB_ + ab) * BOUT_ + o] = acc;
    }
}

#define NB8 768   // l8: OH2 G1 SPB16 -> 6144/16*2
#define NB6 384   // l6: OH1 G1 SPB16
#define NB4 384   // l4: OH1 G2 SPB16
#define NB2 192   // l2: OH1 G4 SPB32
#define NB0 96

__global__ __launch_bounds__(256, 4)
void s2conv_one(const float* __restrict__ x0, const float* __restrict__ x2,
                const float* __restrict__ x4, const float* __restrict__ x6,
                const float* __restrict__ x8,
                const float* __restrict__ w0, const float* __restrict__ w2,
                const float* __restrict__ w4, const float* __restrict__ w6,
                const float* __restrict__ w8,
                const float* __restrict__ bias, float* __restrict__ out,
                size_t off0, size_t off2, size_t off4, size_t off6, size_t off8) {
    __shared__ __attribute__((aligned(16))) float os[BOUT_ * 13 * 13];  // 21.6 KB
    int b = blockIdx.x;                        // big degrees first
    if (b < NB8) { mfma_lds_body<17, 2, 1, 16>(x8, w8, out + off8, os, b); return; }
    b -= NB8;
    if (b < NB6) { mfma_lds_body<13, 1, 1, 16>(x6, w6, out + off6, os, b); return; }
    b -= NB6;
    if (b < NB4) { mfma_lds_body< 9, 1, 2, 16>(x4, w4, out + off4, os, b); return; }
    b -= NB4;
    if (b < NB2) { mfma_lds_body< 5, 1, 4, 32>(x2, w2, out + off2, os, b); return; }
    b -= NB2;
    l0_body(x0, w0, bias, out + off0, b);
}

extern "C" void kernel_launch(void* const* d_in, const int* in_sizes, int n_in,
                              void* d_out, int out_size, void* d_ws, size_t ws_size,
                              hipStream_t stream) {
    const float* x0 = (const float*)d_in[0];
    const float* w0 = (const float*)d_in[1];
    const float* x2 = (const float*)d_in[2];
    const float* w2 = (const float*)d_in[3];
    const float* x4 = (const float*)d_in[4];
    const float* w4 = (const float*)d_in[5];
    const float* x6 = (const float*)d_in[6];
    const float* w6 = (const float*)d_in[7];
    const float* x8 = (const float*)d_in[8];
    const float* w8 = (const float*)d_in[9];
    const float* bias = (const float*)d_in[10];
    float* out = (float*)d_out;

    const size_t per = (size_t)B_ * AB_ * BOUT_;
    size_t off0 = 0;
    size_t off2 = off0 + per * 1;
    size_t off4 = off2 + per * 25;
    size_t off6 = off4 + per * 81;
    size_t off8 = off6 + per * 169;

    const int nblocks = NB8 + NB6 + NB4 + NB2 + NB0;   // 1824
    s2conv_one<<<nblocks, 256, 0, stream>>>(x0, x2, x4, x6, x8,
                                            w0, w2, w4, w6, w8,
                                            bias, out,
                                            off0, off2, off4, off6, off8);
}